// Round 1
// baseline (505.228 us; speedup 1.0000x reference)
//
#include <hip/hip_runtime.h>
#include <math.h>

typedef __attribute__((ext_vector_type(8))) short short8;
typedef __attribute__((ext_vector_type(4))) float f32x4;

#define MFMA16(a, b, c) __builtin_amdgcn_mfma_f32_16x16x32_bf16((a), (b), (c), 0, 0, 0)

static __device__ __forceinline__ unsigned short f2bf(float f) {
  union { float f; unsigned u; } v; v.f = f;
  unsigned r = v.u + 0x7FFFu + ((v.u >> 16) & 1u);
  return (unsigned short)(r >> 16);
}

static __device__ __forceinline__ short8 cvt2v(f32x4 a, f32x4 b) {
  short8 t;
#pragma unroll
  for (int j = 0; j < 4; ++j) t[j] = (short)f2bf(a[j]);
#pragma unroll
  for (int j = 0; j < 4; ++j) t[4 + j] = (short)f2bf(b[j]);
  return t;
}

// C[M,N] = A[M,K=512] @ W[N,K=512]^T + bias, bf16 MFMA, fp32 acc.
// MODE 0: store bf16 to qh/kh layout [B,H,S,64]   (row=b*1024+s, col=h*64+d)
// MODE 1: store bf16 to vt layout   [B,H,64,S]
// MODE 2: store fp32 flat [M,512] (final output)
template <int MODE, bool ABF16>
__global__ __launch_bounds__(256) void gemm_bt(const void* __restrict__ A_,
                                               const float* __restrict__ W,
                                               const float* __restrict__ bias,
                                               void* __restrict__ out_) {
  const int tid = threadIdx.x;
  const int wv = tid >> 6, lane = tid & 63;
  const int lr = lane & 15, lg = lane >> 4;
  const int m0 = blockIdx.x * 128 + (wv >> 1) * 64;
  const int n0 = blockIdx.y * 128 + (wv & 1) * 64;

  f32x4 acc[4][4] = {};

  const float* Af = (const float*)A_;
  const unsigned short* Ab = (const unsigned short*)A_;

  for (int k0 = 0; k0 < 512; k0 += 32) {
    short8 af[4], bw[4];
#pragma unroll
    for (int mi = 0; mi < 4; ++mi) {
      size_t off = (size_t)(m0 + mi * 16 + lr) * 512 + k0 + 8 * lg;
      if constexpr (ABF16) {
        af[mi] = *(const short8*)(Ab + off);
      } else {
        f32x4 p0 = *(const f32x4*)(Af + off);
        f32x4 p1 = *(const f32x4*)(Af + off + 4);
        af[mi] = cvt2v(p0, p1);
      }
    }
#pragma unroll
    for (int ni = 0; ni < 4; ++ni) {
      size_t off = (size_t)(n0 + ni * 16 + lr) * 512 + k0 + 8 * lg;
      f32x4 p0 = *(const f32x4*)(W + off);
      f32x4 p1 = *(const f32x4*)(W + off + 4);
      bw[ni] = cvt2v(p0, p1);
    }
#pragma unroll
    for (int mi = 0; mi < 4; ++mi)
#pragma unroll
      for (int ni = 0; ni < 4; ++ni)
        acc[mi][ni] = MFMA16(af[mi], bw[ni], acc[mi][ni]);
  }

#pragma unroll
  for (int ni = 0; ni < 4; ++ni) {
    const int c = n0 + ni * 16 + lr;
    const float bv = bias[c];
#pragma unroll
    for (int mi = 0; mi < 4; ++mi) {
#pragma unroll
      for (int r = 0; r < 4; ++r) {
        const int rg = m0 + mi * 16 + 4 * lg + r;
        const float val = acc[mi][ni][r] + bv;
        if constexpr (MODE == 2) {
          ((float*)out_)[(size_t)rg * 512 + c] = val;
        } else {
          const int bI = rg >> 10, s = rg & 1023, hI = c >> 6, d = c & 63;
          size_t addr;
          if constexpr (MODE == 0)
            addr = ((size_t)(bI * 8 + hI) * 1024 + s) * 64 + d;
          else
            addr = ((size_t)(bI * 8 + hI) * 64 + d) * 1024 + s;
          ((unsigned short*)out_)[addr] = f2bf(val);
        }
      }
    }
  }
}

// Fused attention: per workgroup = (b, q-tile of 32), 8 waves = 8 heads.
// Loop over 16 k-tiles of 64: QK^T (MFMA) -> LDS logits [8][32][68] ->
// softmax over HEADS -> write attn (fp32, 512MB) + PV accumulate (MFMA).
__global__ __launch_bounds__(512) void attn_fused(
    const unsigned short* __restrict__ qh, const unsigned short* __restrict__ kh,
    const unsigned short* __restrict__ vt, const int* __restrict__ mask,
    float* __restrict__ attn_out, unsigned short* __restrict__ ctx) {
  __shared__ float lds[8][32][68];  // +4 pad: breaks bank alignment, keeps 16B align
  const int tid = threadIdx.x;
  const int h = tid >> 6, lane = tid & 63;
  const int lr = lane & 15, lg = lane >> 4;
  const int b = blockIdx.y, q0 = blockIdx.x * 32;

  const unsigned short* qb = qh + ((size_t)(b * 8 + h) << 16);  // *1024*64
  const unsigned short* kb = kh + ((size_t)(b * 8 + h) << 16);
  const unsigned short* vb = vt + ((size_t)(b * 8 + h) << 16);

  // Q fragments held in registers for whole kernel
  short8 qf[2][2];
#pragma unroll
  for (int mi = 0; mi < 2; ++mi)
#pragma unroll
    for (int ks = 0; ks < 2; ++ks)
      qf[mi][ks] = *(const short8*)(qb + (size_t)(q0 + mi * 16 + lr) * 64 + ks * 32 + 8 * lg);

  f32x4 apv[2][4] = {};

  for (int kt = 0; kt < 16; ++kt) {
    const int k0 = kt * 64;

    // ---- QK^T for this wave's head ----
    f32x4 aqk[2][4] = {};
    short8 kf[4][2];
#pragma unroll
    for (int ni = 0; ni < 4; ++ni)
#pragma unroll
      for (int ks = 0; ks < 2; ++ks)
        kf[ni][ks] = *(const short8*)(kb + (size_t)(k0 + ni * 16 + lr) * 64 + ks * 32 + 8 * lg);
#pragma unroll
    for (int ks = 0; ks < 2; ++ks)
#pragma unroll
      for (int mi = 0; mi < 2; ++mi)
#pragma unroll
        for (int ni = 0; ni < 4; ++ni)
          aqk[mi][ni] = MFMA16(qf[mi][ks], kf[ni][ks], aqk[mi][ni]);

    __syncthreads();  // previous iteration's LDS consumers done

    // ---- write logits: scale 1/sqrt(64) + mask*-1e9 (fp32, faithful) ----
#pragma unroll
    for (int ni = 0; ni < 4; ++ni) {
      const int col = ni * 16 + lr;
      const float mv = -1e9f * (float)mask[b * 1024 + k0 + col];
#pragma unroll
      for (int mi = 0; mi < 2; ++mi)
#pragma unroll
        for (int r = 0; r < 4; ++r)
          lds[h][mi * 16 + 4 * lg + r][col] = aqk[mi][ni][r] * 0.125f + mv;
    }
    __syncthreads();

    // ---- softmax over the 8 heads, per (q,k) ----
#pragma unroll
    for (int p = 0; p < 4; ++p) {
      const int idx = tid + p * 512;  // 2048 (q,k) pairs
      const int q = idx >> 6, k = idx & 63;
      float x[8];
      float m = -3.4e38f;
#pragma unroll
      for (int hh = 0; hh < 8; ++hh) {
        x[hh] = lds[hh][q][k];
        m = fmaxf(m, x[hh]);
      }
      float e[8], s = 0.f;
#pragma unroll
      for (int hh = 0; hh < 8; ++hh) {
        e[hh] = __expf(x[hh] - m);
        s += e[hh];
      }
      const float inv = 1.0f / s;
#pragma unroll
      for (int hh = 0; hh < 8; ++hh) lds[hh][q][k] = e[hh] * inv;
    }
    __syncthreads();

    // ---- coalesced attn write-out (float4) ----
    float* aout = attn_out + ((size_t)b * 8) * 1024 * 1024;
#pragma unroll
    for (int i = 0; i < 8; ++i) {
      const int idx = tid + i * 512;  // 4096 float4s
      const int hh = idx >> 9, q = (idx >> 4) & 31, k4 = idx & 15;
      f32x4 vv = *(const f32x4*)&lds[hh][q][k4 * 4];
      *(f32x4*)(aout + ((size_t)hh * 1024 + q0 + q) * 1024 + k0 + k4 * 4) = vv;
    }

    // ---- PV: attn(tile) @ V, from LDS (fp32->bf16) and vt (bf16) ----
    short8 pf[2][2];
#pragma unroll
    for (int mi = 0; mi < 2; ++mi)
#pragma unroll
      for (int ks = 0; ks < 2; ++ks) {
        const float* pp = &lds[h][mi * 16 + lr][ks * 32 + 8 * lg];
        f32x4 p0 = *(const f32x4*)pp;
        f32x4 p1 = *(const f32x4*)(pp + 4);
        pf[mi][ks] = cvt2v(p0, p1);
      }
    short8 vf[4][2];
#pragma unroll
    for (int ni = 0; ni < 4; ++ni)
#pragma unroll
      for (int ks = 0; ks < 2; ++ks)
        vf[ni][ks] = *(const short8*)(vb + (size_t)(ni * 16 + lr) * 1024 + k0 + ks * 32 + 8 * lg);
#pragma unroll
    for (int ks = 0; ks < 2; ++ks)
#pragma unroll
      for (int mi = 0; mi < 2; ++mi)
#pragma unroll
        for (int ni = 0; ni < 4; ++ni)
          apv[mi][ni] = MFMA16(pf[mi][ks], vf[ni][ks], apv[mi][ni]);
  }

  // ---- write merged ctx [B,S,512] bf16 ----
#pragma unroll
  for (int mi = 0; mi < 2; ++mi)
#pragma unroll
    for (int ni = 0; ni < 4; ++ni)
#pragma unroll
      for (int r = 0; r < 4; ++r) {
        const int row = q0 + mi * 16 + 4 * lg + r;
        const int col = h * 64 + ni * 16 + lr;
        ctx[((size_t)b * 1024 + row) * 512 + col] = f2bf(apv[mi][ni][r]);
      }
}

extern "C" void kernel_launch(void* const* d_in, const int* in_sizes, int n_in,
                              void* d_out, int out_size, void* d_ws, size_t ws_size,
                              hipStream_t stream) {
  const float* q = (const float*)d_in[0];
  const float* k = (const float*)d_in[1];
  const float* v = (const float*)d_in[2];
  const int* mask = (const int*)d_in[3];
  const float* wq_w = (const float*)d_in[4];
  const float* wq_b = (const float*)d_in[5];
  const float* wk_w = (const float*)d_in[6];
  const float* wk_b = (const float*)d_in[7];
  const float* wv_w = (const float*)d_in[8];
  const float* wv_b = (const float*)d_in[9];
  const float* wo_w = (const float*)d_in[10];
  const float* wo_b = (const float*)d_in[11];

  float* out = (float*)d_out;                       // [16,1024,512]
  float* attn = out + (size_t)16 * 1024 * 512;      // [16,8,1024,1024]

  unsigned short* qh = (unsigned short*)d_ws;                 // [16,8,1024,64] bf16
  unsigned short* kh = qh + (size_t)16 * 8 * 1024 * 64;       // [16,8,1024,64]
  unsigned short* vt = kh + (size_t)16 * 8 * 1024 * 64;       // [16,8,64,1024]
  unsigned short* ctx = vt + (size_t)16 * 8 * 1024 * 64;      // [16,1024,512]

  dim3 gp(128, 4), bp(256);
  gemm_bt<0, false><<<gp, bp, 0, stream>>>(q, wq_w, wq_b, qh);
  gemm_bt<0, false><<<gp, bp, 0, stream>>>(k, wk_w, wk_b, kh);
  gemm_bt<1, false><<<gp, bp, 0, stream>>>(v, wv_w, wv_b, vt);
  attn_fused<<<dim3(32, 16), dim3(512), 0, stream>>>(qh, kh, vt, mask, attn, ctx);
  gemm_bt<2, true><<<gp, bp, 0, stream>>>(ctx, wo_w, wo_b, out);
}

// Round 2
// 430.295 us; speedup vs baseline: 1.1741x; 1.1741x over previous
//
#include <hip/hip_runtime.h>
#include <math.h>

typedef __attribute__((ext_vector_type(8))) short short8;
typedef __attribute__((ext_vector_type(4))) float f32x4;
typedef __attribute__((ext_vector_type(4))) int int4_t;
typedef __attribute__((ext_vector_type(4))) unsigned short ushort4_t;

#define MFMA16(a, b, c) __builtin_amdgcn_mfma_f32_16x16x32_bf16((a), (b), (c), 0, 0, 0)

static __device__ __forceinline__ unsigned short f2bf(float f) {
  union { float f; unsigned u; } v; v.f = f;
  unsigned r = v.u + 0x7FFFu + ((v.u >> 16) & 1u);
  return (unsigned short)(r >> 16);
}

static __device__ __forceinline__ short8 cvt2v(f32x4 a, f32x4 b) {
  short8 t;
#pragma unroll
  for (int j = 0; j < 4; ++j) t[j] = (short)f2bf(a[j]);
#pragma unroll
  for (int j = 0; j < 4; ++j) t[4 + j] = (short)f2bf(b[j]);
  return t;
}

// C[M,N] = A[M,K=512] @ W[N,K=512]^T + bias, bf16 MFMA, fp32 acc.
// MODE 0: store bf16 to qh/kh layout [B,H,S,64]
// MODE 1: store bf16 to vt layout   [B,H,64,S]
// MODE 2: store fp32 flat [M,512]
template <int MODE, bool ABF16>
__global__ __launch_bounds__(256) void gemm_bt(const void* __restrict__ A_,
                                               const float* __restrict__ W,
                                               const float* __restrict__ bias,
                                               void* __restrict__ out_) {
  const int tid = threadIdx.x;
  const int wv = tid >> 6, lane = tid & 63;
  const int lr = lane & 15, lg = lane >> 4;
  const int m0 = blockIdx.x * 128 + (wv >> 1) * 64;
  const int n0 = blockIdx.y * 128 + (wv & 1) * 64;

  f32x4 acc[4][4] = {};

  const float* Af = (const float*)A_;
  const unsigned short* Ab = (const unsigned short*)A_;

  for (int k0 = 0; k0 < 512; k0 += 32) {
    short8 af[4], bw[4];
#pragma unroll
    for (int mi = 0; mi < 4; ++mi) {
      size_t off = (size_t)(m0 + mi * 16 + lr) * 512 + k0 + 8 * lg;
      if constexpr (ABF16) {
        af[mi] = *(const short8*)(Ab + off);
      } else {
        f32x4 p0 = *(const f32x4*)(Af + off);
        f32x4 p1 = *(const f32x4*)(Af + off + 4);
        af[mi] = cvt2v(p0, p1);
      }
    }
#pragma unroll
    for (int ni = 0; ni < 4; ++ni) {
      size_t off = (size_t)(n0 + ni * 16 + lr) * 512 + k0 + 8 * lg;
      f32x4 p0 = *(const f32x4*)(W + off);
      f32x4 p1 = *(const f32x4*)(W + off + 4);
      bw[ni] = cvt2v(p0, p1);
    }
#pragma unroll
    for (int mi = 0; mi < 4; ++mi)
#pragma unroll
      for (int ni = 0; ni < 4; ++ni)
        acc[mi][ni] = MFMA16(af[mi], bw[ni], acc[mi][ni]);
  }

#pragma unroll
  for (int ni = 0; ni < 4; ++ni) {
    const int c = n0 + ni * 16 + lr;
    const float bv = bias[c];
#pragma unroll
    for (int mi = 0; mi < 4; ++mi) {
#pragma unroll
      for (int r = 0; r < 4; ++r) {
        const int rg = m0 + mi * 16 + 4 * lg + r;
        const float val = acc[mi][ni][r] + bv;
        if constexpr (MODE == 2) {
          ((float*)out_)[(size_t)rg * 512 + c] = val;
        } else {
          const int bI = rg >> 10, s = rg & 1023, hI = c >> 6, d = c & 63;
          size_t addr;
          if constexpr (MODE == 0)
            addr = ((size_t)(bI * 8 + hI) * 1024 + s) * 64 + d;
          else
            addr = ((size_t)(bI * 8 + hI) * 64 + d) * 1024 + s;
          ((unsigned short*)out_)[addr] = f2bf(val);
        }
      }
    }
  }
}

// Fused attention v2: swapped QK^T (acc k-contiguous) -> all-vector LDS,
// direct-from-register nontemporal attn stores, bf16 prob write-back.
// wg = (b, q-tile of 32), 8 waves = 8 heads; 16 k-tiles of 64.
__global__ __launch_bounds__(512, 2) void attn_fused(
    const unsigned short* __restrict__ qh, const unsigned short* __restrict__ kh,
    const unsigned short* __restrict__ vt, const int* __restrict__ mask,
    float* __restrict__ attn_out, unsigned short* __restrict__ ctx) {
  __shared__ float lt[8][32][68];            // fp32 logits [h][q][k], stride 17 banks
  __shared__ unsigned short pb[8][32][72];   // bf16 probs  [h][q][k]

  const int tid = threadIdx.x;
  const int h = tid >> 6, lane = tid & 63;
  const int lr = lane & 15, lg = lane >> 4;
  const int b = blockIdx.y, q0 = blockIdx.x * 32;

  const unsigned short* qb = qh + ((size_t)(b * 8 + h) << 16);
  const unsigned short* kb = kh + ((size_t)(b * 8 + h) << 16);
  const unsigned short* vb = vt + ((size_t)(b * 8 + h) << 16);
  const int* mrow = mask + b * 1024;

  // Q fragments (B-operand of swapped QK): held all kernel
  short8 qf[2][2];
#pragma unroll
  for (int qi = 0; qi < 2; ++qi)
#pragma unroll
    for (int ks = 0; ks < 2; ++ks)
      qf[qi][ks] = *(const short8*)(qb + (size_t)(q0 + qi * 16 + lr) * 64 + ks * 32 + 8 * lg);

  const int sq = tid >> 4, sk4 = tid & 15;  // softmax ownership: (q=sq, k=4*sk4..+3)

  f32x4 apv[2][4] = {};

  for (int kt = 0; kt < 16; ++kt) {
    const int k0 = kt * 64;

    // ---- swapped QK^T: A = K rows, B = Q rows -> acc[k][q], k contiguous in regs
    short8 kf[4][2];
#pragma unroll
    for (int ki = 0; ki < 4; ++ki)
#pragma unroll
      for (int ks = 0; ks < 2; ++ks)
        kf[ki][ks] = *(const short8*)(kb + (size_t)(k0 + ki * 16 + lr) * 64 + ks * 32 + 8 * lg);
    f32x4 aqk[4][2] = {};
#pragma unroll
    for (int ks = 0; ks < 2; ++ks)
#pragma unroll
      for (int ki = 0; ki < 4; ++ki)
#pragma unroll
        for (int qi = 0; qi < 2; ++qi)
          aqk[ki][qi] = MFMA16(kf[ki][ks], qf[qi][ks], aqk[ki][qi]);

    // mask quads for this thread's k rows (k = ki*16 + 4*lg + r)
    f32x4 mv[4];
#pragma unroll
    for (int ki = 0; ki < 4; ++ki) {
      int4_t mq = *(const int4_t*)(mrow + k0 + ki * 16 + 4 * lg);
#pragma unroll
      for (int r = 0; r < 4; ++r) mv[ki][r] = -1e9f * (float)mq[r];
    }

    __syncthreads();  // prev tile's pb/lt consumers done

    // ---- vectorized logit stores: f32x4 over 4 consecutive k
#pragma unroll
    for (int ki = 0; ki < 4; ++ki)
#pragma unroll
      for (int qi = 0; qi < 2; ++qi) {
        f32x4 v;
#pragma unroll
        for (int r = 0; r < 4; ++r) v[r] = aqk[ki][qi][r] * 0.125f + mv[ki][r];
        *(f32x4*)&lt[h][qi * 16 + lr][ki * 16 + 4 * lg] = v;
      }
    __syncthreads();

    // ---- softmax over 8 heads; thread owns (sq, 4 k)
    f32x4 e[8];
#pragma unroll
    for (int hh = 0; hh < 8; ++hh) e[hh] = *(const f32x4*)&lt[hh][sq][4 * sk4];
    f32x4 mx = e[0];
#pragma unroll
    for (int hh = 1; hh < 8; ++hh)
#pragma unroll
      for (int r = 0; r < 4; ++r) mx[r] = fmaxf(mx[r], e[hh][r]);
    f32x4 s = {0.f, 0.f, 0.f, 0.f};
#pragma unroll
    for (int hh = 0; hh < 8; ++hh) {
#pragma unroll
      for (int r = 0; r < 4; ++r) e[hh][r] = __expf(e[hh][r] - mx[r]);
      s += e[hh];
    }
    f32x4 inv;
#pragma unroll
    for (int r = 0; r < 4; ++r) inv[r] = __builtin_amdgcn_rcpf(s[r]);

    // ---- direct global attn stores (nt) + bf16 prob write-back
    float* abase = attn_out + (((size_t)(b * 8) * 1024 + q0 + sq) * 1024) + k0 + 4 * sk4;
#pragma unroll
    for (int hh = 0; hh < 8; ++hh) {
      f32x4 p = e[hh] * inv;
      __builtin_nontemporal_store(p, (f32x4*)(abase + ((size_t)hh << 20)));
      ushort4_t pk;
#pragma unroll
      for (int r = 0; r < 4; ++r) pk[r] = f2bf(p[r]);
      *(ushort4_t*)&pb[hh][sq][4 * sk4] = pk;
    }
    __syncthreads();

    // ---- PV: A = probs (bf16 from LDS), B = V columns
    short8 pf[2][2];
#pragma unroll
    for (int mi = 0; mi < 2; ++mi)
#pragma unroll
      for (int ks = 0; ks < 2; ++ks)
        pf[mi][ks] = *(const short8*)&pb[h][mi * 16 + lr][ks * 32 + 8 * lg];
    short8 vf[4][2];
#pragma unroll
    for (int ni = 0; ni < 4; ++ni)
#pragma unroll
      for (int ks = 0; ks < 2; ++ks)
        vf[ni][ks] = *(const short8*)(vb + (size_t)(ni * 16 + lr) * 1024 + k0 + ks * 32 + 8 * lg);
#pragma unroll
    for (int ks = 0; ks < 2; ++ks)
#pragma unroll
      for (int mi = 0; mi < 2; ++mi)
#pragma unroll
        for (int ni = 0; ni < 4; ++ni)
          apv[mi][ni] = MFMA16(pf[mi][ks], vf[ni][ks], apv[mi][ni]);
  }

  // ---- write merged ctx [B,S,512] bf16
#pragma unroll
  for (int mi = 0; mi < 2; ++mi)
#pragma unroll
    for (int ni = 0; ni < 4; ++ni)
#pragma unroll
      for (int r = 0; r < 4; ++r) {
        const int row = q0 + mi * 16 + 4 * lg + r;
        const int col = h * 64 + ni * 16 + lr;
        ctx[((size_t)b * 1024 + row) * 512 + col] = f2bf(apv[mi][ni][r]);
      }
}

extern "C" void kernel_launch(void* const* d_in, const int* in_sizes, int n_in,
                              void* d_out, int out_size, void* d_ws, size_t ws_size,
                              hipStream_t stream) {
  const float* q = (const float*)d_in[0];
  const float* k = (const float*)d_in[1];
  const float* v = (const float*)d_in[2];
  const int* mask = (const int*)d_in[3];
  const float* wq_w = (const float*)d_in[4];
  const float* wq_b = (const float*)d_in[5];
  const float* wk_w = (const float*)d_in[6];
  const float* wk_b = (const float*)d_in[7];
  const float* wv_w = (const float*)d_in[8];
  const float* wv_b = (const float*)d_in[9];
  const float* wo_w = (const float*)d_in[10];
  const float* wo_b = (const float*)d_in[11];

  float* out = (float*)d_out;                   // [16,1024,512]
  float* attn = out + (size_t)16 * 1024 * 512;  // [16,8,1024,1024]

  unsigned short* qh = (unsigned short*)d_ws;              // [16,8,1024,64] bf16
  unsigned short* kh = qh + (size_t)16 * 8 * 1024 * 64;    // [16,8,1024,64]
  unsigned short* vt = kh + (size_t)16 * 8 * 1024 * 64;    // [16,8,64,1024]
  unsigned short* ctx = vt + (size_t)16 * 8 * 1024 * 64;   // [16,1024,512]

  dim3 gp(128, 4), bp(256);
  gemm_bt<0, false><<<gp, bp, 0, stream>>>(q, wq_w, wq_b, qh);
  gemm_bt<0, false><<<gp, bp, 0, stream>>>(k, wk_w, wk_b, kh);
  gemm_bt<1, false><<<gp, bp, 0, stream>>>(v, wv_w, wv_b, vt);
  attn_fused<<<dim3(32, 16), dim3(512), 0, stream>>>(qh, kh, vt, mask, attn, ctx);
  gemm_bt<2, true><<<gp, bp, 0, stream>>>(ctx, wo_w, wo_b, out);
}

// Round 3
// 407.522 us; speedup vs baseline: 1.2398x; 1.0559x over previous
//
#include <hip/hip_runtime.h>
#include <math.h>

typedef __attribute__((ext_vector_type(8))) short short8;
typedef __attribute__((ext_vector_type(4))) float f32x4;
typedef __attribute__((ext_vector_type(4))) int int4_t;
typedef __attribute__((ext_vector_type(4))) unsigned short ushort4_t;

#define MFMA16(a, b, c) __builtin_amdgcn_mfma_f32_16x16x32_bf16((a), (b), (c), 0, 0, 0)

static __device__ __forceinline__ unsigned short f2bf(float f) {
  union { float f; unsigned u; } v; v.f = f;
  unsigned r = v.u + 0x7FFFu + ((v.u >> 16) & 1u);
  return (unsigned short)(r >> 16);
}

static __device__ __forceinline__ float bf2f(unsigned short b) {
  union { unsigned u; float f; } v; v.u = ((unsigned)b) << 16;
  return v.f;
}

static __device__ __forceinline__ short8 cvt2v(f32x4 a, f32x4 b) {
  short8 t;
#pragma unroll
  for (int j = 0; j < 4; ++j) t[j] = (short)f2bf(a[j]);
#pragma unroll
  for (int j = 0; j < 4; ++j) t[4 + j] = (short)f2bf(b[j]);
  return t;
}

// C[M,N] = A[M,K=512] @ W[N,K=512]^T + bias, bf16 MFMA, fp32 acc.
// MODE 0: store bf16 to qh/kh layout [B,H,S,64]
// MODE 1: store bf16 to vt layout   [B,H,64,S]
// MODE 2: store fp32 flat [M,512]
template <int MODE, bool ABF16>
__global__ __launch_bounds__(256) void gemm_bt(const void* __restrict__ A_,
                                               const float* __restrict__ W,
                                               const float* __restrict__ bias,
                                               void* __restrict__ out_) {
  const int tid = threadIdx.x;
  const int wv = tid >> 6, lane = tid & 63;
  const int lr = lane & 15, lg = lane >> 4;
  const int m0 = blockIdx.x * 128 + (wv >> 1) * 64;
  const int n0 = blockIdx.y * 128 + (wv & 1) * 64;

  f32x4 acc[4][4] = {};

  const float* Af = (const float*)A_;
  const unsigned short* Ab = (const unsigned short*)A_;

  for (int k0 = 0; k0 < 512; k0 += 32) {
    short8 af[4], bw[4];
#pragma unroll
    for (int mi = 0; mi < 4; ++mi) {
      size_t off = (size_t)(m0 + mi * 16 + lr) * 512 + k0 + 8 * lg;
      if constexpr (ABF16) {
        af[mi] = *(const short8*)(Ab + off);
      } else {
        f32x4 p0 = *(const f32x4*)(Af + off);
        f32x4 p1 = *(const f32x4*)(Af + off + 4);
        af[mi] = cvt2v(p0, p1);
      }
    }
#pragma unroll
    for (int ni = 0; ni < 4; ++ni) {
      size_t off = (size_t)(n0 + ni * 16 + lr) * 512 + k0 + 8 * lg;
      f32x4 p0 = *(const f32x4*)(W + off);
      f32x4 p1 = *(const f32x4*)(W + off + 4);
      bw[ni] = cvt2v(p0, p1);
    }
#pragma unroll
    for (int mi = 0; mi < 4; ++mi)
#pragma unroll
      for (int ni = 0; ni < 4; ++ni)
        acc[mi][ni] = MFMA16(af[mi], bw[ni], acc[mi][ni]);
  }

#pragma unroll
  for (int ni = 0; ni < 4; ++ni) {
    const int c = n0 + ni * 16 + lr;
    const float bv = bias[c];
#pragma unroll
    for (int mi = 0; mi < 4; ++mi) {
#pragma unroll
      for (int r = 0; r < 4; ++r) {
        const int rg = m0 + mi * 16 + 4 * lg + r;
        const float val = acc[mi][ni][r] + bv;
        if constexpr (MODE == 2) {
          ((float*)out_)[(size_t)rg * 512 + c] = val;
        } else {
          const int bI = rg >> 10, s = rg & 1023, hI = c >> 6, d = c & 63;
          size_t addr;
          if constexpr (MODE == 0)
            addr = ((size_t)(bI * 8 + hI) * 1024 + s) * 64 + d;
          else
            addr = ((size_t)(bI * 8 + hI) * 64 + d) * 1024 + s;
          ((unsigned short*)out_)[addr] = f2bf(val);
        }
      }
    }
  }
}

// Fused attention v3: single bf16 LDS buffer (36.8KB -> 2 blocks/CU),
// swapped QK^T (k-contiguous acc), in-place prob write-back,
// direct nontemporal attn stores, XCD-swizzled work assignment.
__global__ __launch_bounds__(512, 4) void attn_fused(
    const unsigned short* __restrict__ qh, const unsigned short* __restrict__ kh,
    const unsigned short* __restrict__ vt, const int* __restrict__ mask,
    float* __restrict__ attn_out, unsigned short* __restrict__ ctx) {
  __shared__ unsigned short sb[8][32][72];  // bf16 logits -> probs, [h][q][k]

  const int tid = threadIdx.x;
  const int h = tid >> 6, lane = tid & 63;
  const int lr = lane & 15, lg = lane >> 4;

  // XCD swizzle: each XCD (lin&7) owns exactly 2 batches -> K/V L2-resident
  const int lin = blockIdx.x + 32 * blockIdx.y;
  const int xcd = lin & 7, slot = lin >> 3;
  const int b = xcd + 8 * (slot >> 5);
  const int q0 = (slot & 31) * 32;

  const unsigned short* qb = qh + ((size_t)(b * 8 + h) << 16);
  const unsigned short* kb = kh + ((size_t)(b * 8 + h) << 16);
  const unsigned short* vb = vt + ((size_t)(b * 8 + h) << 16);
  const int* mrow = mask + b * 1024;

  // Q fragments (B-operand of swapped QK): held all kernel
  short8 qf[2][2];
#pragma unroll
  for (int qi = 0; qi < 2; ++qi)
#pragma unroll
    for (int ks = 0; ks < 2; ++ks)
      qf[qi][ks] = *(const short8*)(qb + (size_t)(q0 + qi * 16 + lr) * 64 + ks * 32 + 8 * lg);

  const int sq = tid >> 4, sk4 = tid & 15;  // softmax ownership: (q=sq, k=4*sk4..+3)

  f32x4 apv[2][4] = {};

  for (int kt = 0; kt < 16; ++kt) {
    const int k0 = kt * 64;

    // ---- swapped QK^T: A = K rows, B = Q rows -> acc[k][q], k contiguous
    short8 kf[4][2];
#pragma unroll
    for (int ki = 0; ki < 4; ++ki)
#pragma unroll
      for (int ks = 0; ks < 2; ++ks)
        kf[ki][ks] = *(const short8*)(kb + (size_t)(k0 + ki * 16 + lr) * 64 + ks * 32 + 8 * lg);
    f32x4 aqk[4][2] = {};
#pragma unroll
    for (int ks = 0; ks < 2; ++ks)
#pragma unroll
      for (int ki = 0; ki < 4; ++ki)
#pragma unroll
        for (int qi = 0; qi < 2; ++qi)
          aqk[ki][qi] = MFMA16(kf[ki][ks], qf[qi][ks], aqk[ki][qi]);

    __syncthreads();  // prev tile's PV reads done (WAR on sb)

    // ---- logit stores: scale + mask in fp32, quantize bf16, ushort4 per 4 k
#pragma unroll
    for (int ki = 0; ki < 4; ++ki) {
      int4_t mq = *(const int4_t*)(mrow + k0 + ki * 16 + 4 * lg);
      f32x4 mv;
#pragma unroll
      for (int r = 0; r < 4; ++r) mv[r] = -1e9f * (float)mq[r];
#pragma unroll
      for (int qi = 0; qi < 2; ++qi) {
        ushort4_t pk;
#pragma unroll
        for (int r = 0; r < 4; ++r) pk[r] = f2bf(aqk[ki][qi][r] * 0.125f + mv[r]);
        *(ushort4_t*)&sb[h][qi * 16 + lr][ki * 16 + 4 * lg] = pk;
      }
    }
    __syncthreads();

    // ---- softmax over 8 heads; thread owns (sq, 4 k); in-place write-back
    f32x4 e[8];
#pragma unroll
    for (int hh = 0; hh < 8; ++hh) {
      ushort4_t raw = *(const ushort4_t*)&sb[hh][sq][4 * sk4];
#pragma unroll
      for (int r = 0; r < 4; ++r) e[hh][r] = bf2f(raw[r]);
    }
    f32x4 mx = e[0];
#pragma unroll
    for (int hh = 1; hh < 8; ++hh)
#pragma unroll
      for (int r = 0; r < 4; ++r) mx[r] = fmaxf(mx[r], e[hh][r]);
    f32x4 s = {0.f, 0.f, 0.f, 0.f};
#pragma unroll
    for (int hh = 0; hh < 8; ++hh) {
#pragma unroll
      for (int r = 0; r < 4; ++r) e[hh][r] = __expf(e[hh][r] - mx[r]);
      s += e[hh];
    }
    f32x4 inv;
#pragma unroll
    for (int r = 0; r < 4; ++r) inv[r] = __builtin_amdgcn_rcpf(s[r]);

    float* abase = attn_out + (((size_t)(b * 8) * 1024 + q0 + sq) * 1024) + k0 + 4 * sk4;
#pragma unroll
    for (int hh = 0; hh < 8; ++hh) {
      f32x4 p = e[hh] * inv;
      __builtin_nontemporal_store(p, (f32x4*)(abase + ((size_t)hh << 20)));
      ushort4_t pk;
#pragma unroll
      for (int r = 0; r < 4; ++r) pk[r] = f2bf(p[r]);
      *(ushort4_t*)&sb[hh][sq][4 * sk4] = pk;  // same thread re-writes -> no barrier
    }
    __syncthreads();

    // ---- PV: A = probs (bf16 LDS), B = V columns
    short8 pf[2][2];
#pragma unroll
    for (int mi = 0; mi < 2; ++mi)
#pragma unroll
      for (int ks = 0; ks < 2; ++ks)
        pf[mi][ks] = *(const short8*)&sb[h][mi * 16 + lr][ks * 32 + 8 * lg];
    short8 vf[4][2];
#pragma unroll
    for (int ni = 0; ni < 4; ++ni)
#pragma unroll
      for (int ks = 0; ks < 2; ++ks)
        vf[ni][ks] = *(const short8*)(vb + (size_t)(ni * 16 + lr) * 1024 + k0 + ks * 32 + 8 * lg);
#pragma unroll
    for (int ks = 0; ks < 2; ++ks)
#pragma unroll
      for (int mi = 0; mi < 2; ++mi)
#pragma unroll
        for (int ni = 0; ni < 4; ++ni)
          apv[mi][ni] = MFMA16(pf[mi][ks], vf[ni][ks], apv[mi][ni]);
  }

  // ---- write merged ctx [B,S,512] bf16
#pragma unroll
  for (int mi = 0; mi < 2; ++mi)
#pragma unroll
    for (int ni = 0; ni < 4; ++ni)
#pragma unroll
      for (int r = 0; r < 4; ++r) {
        const int row = q0 + mi * 16 + 4 * lg + r;
        const int col = h * 64 + ni * 16 + lr;
        ctx[((size_t)b * 1024 + row) * 512 + col] = f2bf(apv[mi][ni][r]);
      }
}

extern "C" void kernel_launch(void* const* d_in, const int* in_sizes, int n_in,
                              void* d_out, int out_size, void* d_ws, size_t ws_size,
                              hipStream_t stream) {
  const float* q = (const float*)d_in[0];
  const float* k = (const float*)d_in[1];
  const float* v = (const float*)d_in[2];
  const int* mask = (const int*)d_in[3];
  const float* wq_w = (const float*)d_in[4];
  const float* wq_b = (const float*)d_in[5];
  const float* wk_w = (const float*)d_in[6];
  const float* wk_b = (const float*)d_in[7];
  const float* wv_w = (const float*)d_in[8];
  const float* wv_b = (const float*)d_in[9];
  const float* wo_w = (const float*)d_in[10];
  const float* wo_b = (const float*)d_in[11];

  float* out = (float*)d_out;                   // [16,1024,512]
  float* attn = out + (size_t)16 * 1024 * 512;  // [16,8,1024,1024]

  unsigned short* qh = (unsigned short*)d_ws;              // [16,8,1024,64] bf16
  unsigned short* kh = qh + (size_t)16 * 8 * 1024 * 64;    // [16,8,1024,64]
  unsigned short* vt = kh + (size_t)16 * 8 * 1024 * 64;    // [16,8,64,1024]
  unsigned short* ctx = vt + (size_t)16 * 8 * 1024 * 64;   // [16,1024,512]

  dim3 gp(128, 4), bp(256);
  gemm_bt<0, false><<<gp, bp, 0, stream>>>(q, wq_w, wq_b, qh);
  gemm_bt<0, false><<<gp, bp, 0, stream>>>(k, wk_w, wk_b, kh);
  gemm_bt<1, false><<<gp, bp, 0, stream>>>(v, wv_w, wv_b, vt);
  attn_fused<<<dim3(32, 16), dim3(512), 0, stream>>>(qh, kh, vt, mask, attn, ctx);
  gemm_bt<2, true><<<gp, bp, 0, stream>>>(ctx, wo_w, wo_b, out);
}

// Round 5
// 354.304 us; speedup vs baseline: 1.4260x; 1.1502x over previous
//
#include <hip/hip_runtime.h>
#include <math.h>

typedef __attribute__((ext_vector_type(8))) short short8;
typedef __attribute__((ext_vector_type(4))) float f32x4;
typedef __attribute__((ext_vector_type(4))) int int4_t;
typedef __attribute__((ext_vector_type(4))) unsigned short ushort4_t;

#define MFMA16(a, b, c) __builtin_amdgcn_mfma_f32_16x16x32_bf16((a), (b), (c), 0, 0, 0)

static __device__ __forceinline__ unsigned short f2bf(float f) {
  union { float f; unsigned u; } v; v.f = f;
  unsigned r = v.u + 0x7FFFu + ((v.u >> 16) & 1u);
  return (unsigned short)(r >> 16);
}

static __device__ __forceinline__ float bf2f(unsigned short b) {
  union { unsigned u; float f; } v; v.u = ((unsigned)b) << 16;
  return v.f;
}

static __device__ __forceinline__ short8 cvt2v(f32x4 a, f32x4 b) {
  short8 t;
#pragma unroll
  for (int j = 0; j < 4; ++j) t[j] = (short)f2bf(a[j]);
#pragma unroll
  for (int j = 0; j < 4; ++j) t[4 + j] = (short)f2bf(b[j]);
  return t;
}

// One-shot fp32->bf16 conversion of q,k,v (4096 blocks each) and the four
// weight matrices (128 blocks each). 2048 elems per block (256 thr x 8).
__global__ __launch_bounds__(256) void cvt7(
    const float* __restrict__ q, const float* __restrict__ k, const float* __restrict__ v,
    const float* __restrict__ wq, const float* __restrict__ wk,
    const float* __restrict__ wv, const float* __restrict__ wo,
    unsigned short* __restrict__ qb, unsigned short* __restrict__ kb,
    unsigned short* __restrict__ vb, unsigned short* __restrict__ wqb,
    unsigned short* __restrict__ wkb, unsigned short* __restrict__ wvb,
    unsigned short* __restrict__ wob) {
  const int blk = blockIdx.x;
  const float* src;
  unsigned short* dst;
  size_t base;
  if (blk < 4096)        { src = q;  dst = qb;  base = (size_t)blk * 2048; }
  else if (blk < 8192)   { src = k;  dst = kb;  base = (size_t)(blk - 4096) * 2048; }
  else if (blk < 12288)  { src = v;  dst = vb;  base = (size_t)(blk - 8192) * 2048; }
  else if (blk < 12416)  { src = wq; dst = wqb; base = (size_t)(blk - 12288) * 2048; }
  else if (blk < 12544)  { src = wk; dst = wkb; base = (size_t)(blk - 12416) * 2048; }
  else if (blk < 12672)  { src = wv; dst = wvb; base = (size_t)(blk - 12544) * 2048; }
  else                   { src = wo; dst = wob; base = (size_t)(blk - 12672) * 2048; }
  const size_t i = base + (size_t)threadIdx.x * 8;
  f32x4 a = *(const f32x4*)(src + i);
  f32x4 b = *(const f32x4*)(src + i + 4);
  *(short8*)(dst + i) = cvt2v(a, b);
}

// Pure-bf16 C[M,N] = A[M,512] @ W[N,512]^T + bias. fp32 acc.
// MODE 0: store bf16 [B,H,S,64]; MODE 1: bf16 [B,H,64,S]; MODE 2: fp32 [M,512]
template <int MODE>
__global__ __launch_bounds__(256, 4) void gemm_bt(const unsigned short* __restrict__ A,
                                                  const unsigned short* __restrict__ W,
                                                  const float* __restrict__ bias,
                                                  void* __restrict__ out_) {
  const int tid = threadIdx.x;
  const int wv = tid >> 6, lane = tid & 63;
  const int lr = lane & 15, lg = lane >> 4;
  const int m0 = blockIdx.x * 128 + (wv >> 1) * 64;
  const int n0 = blockIdx.y * 128 + (wv & 1) * 64;

  f32x4 acc[4][4] = {};

  for (int k0 = 0; k0 < 512; k0 += 32) {
    short8 af[4], bw[4];
#pragma unroll
    for (int mi = 0; mi < 4; ++mi)
      af[mi] = *(const short8*)(A + (size_t)(m0 + mi * 16 + lr) * 512 + k0 + 8 * lg);
#pragma unroll
    for (int ni = 0; ni < 4; ++ni)
      bw[ni] = *(const short8*)(W + (size_t)(n0 + ni * 16 + lr) * 512 + k0 + 8 * lg);
#pragma unroll
    for (int mi = 0; mi < 4; ++mi)
#pragma unroll
      for (int ni = 0; ni < 4; ++ni)
        acc[mi][ni] = MFMA16(af[mi], bw[ni], acc[mi][ni]);
  }

#pragma unroll
  for (int ni = 0; ni < 4; ++ni) {
    const int c = n0 + ni * 16 + lr;
    const float bv = bias[c];
#pragma unroll
    for (int mi = 0; mi < 4; ++mi) {
#pragma unroll
      for (int r = 0; r < 4; ++r) {
        const int rg = m0 + mi * 16 + 4 * lg + r;
        const float val = acc[mi][ni][r] + bv;
        if constexpr (MODE == 2) {
          ((float*)out_)[(size_t)rg * 512 + c] = val;
        } else {
          const int bI = rg >> 10, s = rg & 1023, hI = c >> 6, d = c & 63;
          size_t addr;
          if constexpr (MODE == 0)
            addr = ((size_t)(bI * 8 + hI) * 1024 + s) * 64 + d;
          else
            addr = ((size_t)(bI * 8 + hI) * 64 + d) * 1024 + s;
          ((unsigned short*)out_)[addr] = f2bf(val);
        }
      }
    }
  }
}

// Fused attention v3: single bf16 LDS buffer (2 blk/CU), swapped QK^T
// (k-contiguous acc), in-place prob write-back, direct nontemporal attn
// stores, XCD-swizzled work assignment.
__global__ __launch_bounds__(512, 4) void attn_fused(
    const unsigned short* __restrict__ qh, const unsigned short* __restrict__ kh,
    const unsigned short* __restrict__ vt, const int* __restrict__ mask,
    float* __restrict__ attn_out, unsigned short* __restrict__ ctx) {
  __shared__ unsigned short sb[8][32][72];  // bf16 logits -> probs, [h][q][k]

  const int tid = threadIdx.x;
  const int h = tid >> 6, lane = tid & 63;
  const int lr = lane & 15, lg = lane >> 4;

  const int lin = blockIdx.x + 32 * blockIdx.y;
  const int xcd = lin & 7, slot = lin >> 3;
  const int b = xcd + 8 * (slot >> 5);
  const int q0 = (slot & 31) * 32;

  const unsigned short* qb = qh + ((size_t)(b * 8 + h) << 16);
  const unsigned short* kb = kh + ((size_t)(b * 8 + h) << 16);
  const unsigned short* vb = vt + ((size_t)(b * 8 + h) << 16);
  const int* mrow = mask + b * 1024;

  short8 qf[2][2];
#pragma unroll
  for (int qi = 0; qi < 2; ++qi)
#pragma unroll
    for (int ks = 0; ks < 2; ++ks)
      qf[qi][ks] = *(const short8*)(qb + (size_t)(q0 + qi * 16 + lr) * 64 + ks * 32 + 8 * lg);

  const int sq = tid >> 4, sk4 = tid & 15;

  f32x4 apv[2][4] = {};

  for (int kt = 0; kt < 16; ++kt) {
    const int k0 = kt * 64;

    short8 kf[4][2];
#pragma unroll
    for (int ki = 0; ki < 4; ++ki)
#pragma unroll
      for (int ks = 0; ks < 2; ++ks)
        kf[ki][ks] = *(const short8*)(kb + (size_t)(k0 + ki * 16 + lr) * 64 + ks * 32 + 8 * lg);
    f32x4 aqk[4][2] = {};
#pragma unroll
    for (int ks = 0; ks < 2; ++ks)
#pragma unroll
      for (int ki = 0; ki < 4; ++ki)
#pragma unroll
        for (int qi = 0; qi < 2; ++qi)
          aqk[ki][qi] = MFMA16(kf[ki][ks], qf[qi][ks], aqk[ki][qi]);

    __syncthreads();  // prev tile's PV reads done (WAR on sb)

#pragma unroll
    for (int ki = 0; ki < 4; ++ki) {
      int4_t mq = *(const int4_t*)(mrow + k0 + ki * 16 + 4 * lg);
      f32x4 mv;
#pragma unroll
      for (int r = 0; r < 4; ++r) mv[r] = -1e9f * (float)mq[r];
#pragma unroll
      for (int qi = 0; qi < 2; ++qi) {
        ushort4_t pk;
#pragma unroll
        for (int r = 0; r < 4; ++r) pk[r] = f2bf(aqk[ki][qi][r] * 0.125f + mv[r]);
        *(ushort4_t*)&sb[h][qi * 16 + lr][ki * 16 + 4 * lg] = pk;
      }
    }
    __syncthreads();

    f32x4 e[8];
#pragma unroll
    for (int hh = 0; hh < 8; ++hh) {
      ushort4_t raw = *(const ushort4_t*)&sb[hh][sq][4 * sk4];
#pragma unroll
      for (int r = 0; r < 4; ++r) e[hh][r] = bf2f(raw[r]);
    }
    f32x4 mx = e[0];
#pragma unroll
    for (int hh = 1; hh < 8; ++hh)
#pragma unroll
      for (int r = 0; r < 4; ++r) mx[r] = fmaxf(mx[r], e[hh][r]);
    f32x4 s = {0.f, 0.f, 0.f, 0.f};
#pragma unroll
    for (int hh = 0; hh < 8; ++hh) {
#pragma unroll
      for (int r = 0; r < 4; ++r) e[hh][r] = __expf(e[hh][r] - mx[r]);
      s += e[hh];
    }
    f32x4 inv;
#pragma unroll
    for (int r = 0; r < 4; ++r) inv[r] = __builtin_amdgcn_rcpf(s[r]);

    float* abase = attn_out + (((size_t)(b * 8) * 1024 + q0 + sq) * 1024) + k0 + 4 * sk4;
#pragma unroll
    for (int hh = 0; hh < 8; ++hh) {
      f32x4 p = e[hh] * inv;
      __builtin_nontemporal_store(p, (f32x4*)(abase + ((size_t)hh << 20)));
      ushort4_t pk;
#pragma unroll
      for (int r = 0; r < 4; ++r) pk[r] = f2bf(p[r]);
      *(ushort4_t*)&sb[hh][sq][4 * sk4] = pk;
    }
    __syncthreads();

    short8 pf[2][2];
#pragma unroll
    for (int mi = 0; mi < 2; ++mi)
#pragma unroll
      for (int ks = 0; ks < 2; ++ks)
        pf[mi][ks] = *(const short8*)&sb[h][mi * 16 + lr][ks * 32 + 8 * lg];
    short8 vf[4][2];
#pragma unroll
    for (int ni = 0; ni < 4; ++ni)
#pragma unroll
      for (int ks = 0; ks < 2; ++ks)
        vf[ni][ks] = *(const short8*)(vb + (size_t)(ni * 16 + lr) * 1024 + k0 + ks * 32 + 8 * lg);
#pragma unroll
    for (int ks = 0; ks < 2; ++ks)
#pragma unroll
      for (int mi = 0; mi < 2; ++mi)
#pragma unroll
        for (int ni = 0; ni < 4; ++ni)
          apv[mi][ni] = MFMA16(pf[mi][ks], vf[ni][ks], apv[mi][ni]);
  }

#pragma unroll
  for (int mi = 0; mi < 2; ++mi)
#pragma unroll
    for (int ni = 0; ni < 4; ++ni)
#pragma unroll
      for (int r = 0; r < 4; ++r) {
        const int row = q0 + mi * 16 + 4 * lg + r;
        const int col = h * 64 + ni * 16 + lr;
        ctx[((size_t)b * 1024 + row) * 512 + col] = f2bf(apv[mi][ni][r]);
      }
}

extern "C" void kernel_launch(void* const* d_in, const int* in_sizes, int n_in,
                              void* d_out, int out_size, void* d_ws, size_t ws_size,
                              hipStream_t stream) {
  const float* q = (const float*)d_in[0];
  const float* k = (const float*)d_in[1];
  const float* v = (const float*)d_in[2];
  const int* mask = (const int*)d_in[3];
  const float* wq_w = (const float*)d_in[4];
  const float* wq_b = (const float*)d_in[5];
  const float* wk_w = (const float*)d_in[6];
  const float* wk_b = (const float*)d_in[7];
  const float* wv_w = (const float*)d_in[8];
  const float* wv_b = (const float*)d_in[9];
  const float* wo_w = (const float*)d_in[10];
  const float* wo_b = (const float*)d_in[11];

  float* out = (float*)d_out;                   // [16,1024,512]
  float* attn = out + (size_t)16 * 1024 * 512;  // [16,8,1024,1024] fp32

  // bf16 staging for buffers whose LAST consumer runs BEFORE attn_fused,
  // carved from the tail of the attn region (attn_fused overwrites it all):
  // q,k,v (3 x 8,388,608) + wq,wk,wv (3 x 262,144) = 25,952,256 ushorts
  // = 12,976,128 floats.
  unsigned short* qb16 = (unsigned short*)(attn + (134217728 - 12976128));
  unsigned short* kb16 = qb16 + (size_t)16 * 1024 * 512;
  unsigned short* vb16 = kb16 + (size_t)16 * 1024 * 512;
  unsigned short* wq16 = vb16 + (size_t)16 * 1024 * 512;
  unsigned short* wk16 = wq16 + 262144;
  unsigned short* wv16 = wk16 + 262144;

  unsigned short* qh = (unsigned short*)d_ws;              // [16,8,1024,64] bf16
  unsigned short* kh = qh + (size_t)16 * 8 * 1024 * 64;    // [16,8,1024,64]
  unsigned short* vt = kh + (size_t)16 * 8 * 1024 * 64;    // [16,8,64,1024]
  unsigned short* ctx = vt + (size_t)16 * 8 * 1024 * 64;   // [16,1024,512]
  unsigned short* wo16 = ctx + (size_t)16 * 1024 * 512;    // survives attn_fused

  cvt7<<<dim3(12800), dim3(256), 0, stream>>>(q, k, v, wq_w, wk_w, wv_w, wo_w,
                                              qb16, kb16, vb16, wq16, wk16, wv16, wo16);

  dim3 gp(128, 4), bp(256);
  gemm_bt<0><<<gp, bp, 0, stream>>>(qb16, wq16, wq_b, qh);
  gemm_bt<0><<<gp, bp, 0, stream>>>(kb16, wk16, wk_b, kh);
  gemm_bt<1><<<gp, bp, 0, stream>>>(vb16, wv16, wv_b, vt);
  attn_fused<<<dim3(32, 16), dim3(512), 0, stream>>>(qh, kh, vt, mask, attn, ctx);
  gemm_bt<2><<<gp, bp, 0, stream>>>(ctx, wo16, wo_b, out);
}

// Round 6
// 271.439 us; speedup vs baseline: 1.8613x; 1.3053x over previous
//
#include <hip/hip_runtime.h>
#include <math.h>

typedef __attribute__((ext_vector_type(8))) short short8;
typedef __attribute__((ext_vector_type(4))) float f32x4;
typedef __attribute__((ext_vector_type(4))) int int4_t;
typedef __attribute__((ext_vector_type(4))) unsigned short ushort4_t;

#define MFMA16(a, b, c) __builtin_amdgcn_mfma_f32_16x16x32_bf16((a), (b), (c), 0, 0, 0)

// coalesced global->LDS DMA, 16B per lane; LDS dest is wave-uniform base + lane*16
#define GLOAD_LDS16(src, ldsbase)                                                     \
  __builtin_amdgcn_global_load_lds(                                                   \
      (const __attribute__((address_space(1))) void*)(src),                           \
      (__attribute__((address_space(3))) void*)(ldsbase), 16, 0, 0)

static __device__ __forceinline__ unsigned short f2bf(float f) {
  union { float f; unsigned u; } v; v.f = f;
  unsigned r = v.u + 0x7FFFu + ((v.u >> 16) & 1u);
  return (unsigned short)(r >> 16);
}

static __device__ __forceinline__ float bf2f(unsigned short b) {
  union { unsigned u; float f; } v; v.u = ((unsigned)b) << 16;
  return v.f;
}

static __device__ __forceinline__ short8 cvt2v(f32x4 a, f32x4 b) {
  short8 t;
#pragma unroll
  for (int j = 0; j < 4; ++j) t[j] = (short)f2bf(a[j]);
#pragma unroll
  for (int j = 0; j < 4; ++j) t[4 + j] = (short)f2bf(b[j]);
  return t;
}

// One-shot fp32->bf16 conversion of q,k,v and the four weight matrices.
__global__ __launch_bounds__(256) void cvt7(
    const float* __restrict__ q, const float* __restrict__ k, const float* __restrict__ v,
    const float* __restrict__ wq, const float* __restrict__ wk,
    const float* __restrict__ wv, const float* __restrict__ wo,
    unsigned short* __restrict__ qb, unsigned short* __restrict__ kb,
    unsigned short* __restrict__ vb, unsigned short* __restrict__ wqb,
    unsigned short* __restrict__ wkb, unsigned short* __restrict__ wvb,
    unsigned short* __restrict__ wob) {
  const int blk = blockIdx.x;
  const float* src;
  unsigned short* dst;
  size_t base;
  if (blk < 4096)        { src = q;  dst = qb;  base = (size_t)blk * 2048; }
  else if (blk < 8192)   { src = k;  dst = kb;  base = (size_t)(blk - 4096) * 2048; }
  else if (blk < 12288)  { src = v;  dst = vb;  base = (size_t)(blk - 8192) * 2048; }
  else if (blk < 12416)  { src = wq; dst = wqb; base = (size_t)(blk - 12288) * 2048; }
  else if (blk < 12544)  { src = wk; dst = wkb; base = (size_t)(blk - 12416) * 2048; }
  else if (blk < 12672)  { src = wv; dst = wvb; base = (size_t)(blk - 12544) * 2048; }
  else                   { src = wo; dst = wob; base = (size_t)(blk - 12672) * 2048; }
  const size_t i = base + (size_t)threadIdx.x * 8;
  f32x4 a = *(const f32x4*)(src + i);
  f32x4 b = *(const f32x4*)(src + i + 4);
  *(short8*)(dst + i) = cvt2v(a, b);
}

// LDS-staged bf16 GEMM: C[M,N] = A[M,512] @ W[N,512]^T + bias, fp32 acc.
// 128x128 tile, BK=64, global_load_lds staging, ds_read_b128 fragments.
// MODE 0: store bf16 fragment-major qh/kh layout (see attn_fused)
// MODE 1: store bf16 fragment-major vt layout
// MODE 2: store fp32 flat [M,512]
template <int MODE>
__global__ __launch_bounds__(256) void gemm_bt(const unsigned short* __restrict__ A,
                                               const unsigned short* __restrict__ W,
                                               const float* __restrict__ bias,
                                               void* __restrict__ out_) {
  __shared__ unsigned short As[128 * 64], Ws[128 * 64];
  const int tid = threadIdx.x;
  const int wv = tid >> 6, lane = tid & 63;
  const int lr = lane & 15, lg = lane >> 4;
  const int m0 = blockIdx.x * 128, n0 = blockIdx.y * 128;
  const int wm = (wv >> 1) * 64, wn = (wv & 1) * 64;

  f32x4 acc[4][4] = {};

  for (int k0 = 0; k0 < 512; k0 += 64) {
    // stage A-tile [128][64] and W-tile [128][64]: 4 passes x 4 waves x 8 rows
#pragma unroll
    for (int p = 0; p < 4; ++p) {
      const int row = (p * 4 + wv) * 8 + (lane >> 3);
      const int col = (lane & 7) * 8;
      GLOAD_LDS16(A + (size_t)(m0 + row) * 512 + k0 + col, &As[(p * 4 + wv) * 512]);
      GLOAD_LDS16(W + (size_t)(n0 + row) * 512 + k0 + col, &Ws[(p * 4 + wv) * 512]);
    }
    __syncthreads();

#pragma unroll
    for (int ks = 0; ks < 2; ++ks) {
      short8 af[4], bw[4];
#pragma unroll
      for (int mi = 0; mi < 4; ++mi)
        af[mi] = *(const short8*)&As[(wm + mi * 16 + lr) * 64 + ks * 32 + lg * 8];
#pragma unroll
      for (int ni = 0; ni < 4; ++ni)
        bw[ni] = *(const short8*)&Ws[(wn + ni * 16 + lr) * 64 + ks * 32 + lg * 8];
#pragma unroll
      for (int mi = 0; mi < 4; ++mi)
#pragma unroll
        for (int ni = 0; ni < 4; ++ni)
          acc[mi][ni] = MFMA16(af[mi], bw[ni], acc[mi][ni]);
    }
    __syncthreads();
  }

#pragma unroll
  for (int ni = 0; ni < 4; ++ni) {
    const int c = n0 + wn + ni * 16 + lr;
    const float bv = bias[c];
#pragma unroll
    for (int mi = 0; mi < 4; ++mi) {
#pragma unroll
      for (int r = 0; r < 4; ++r) {
        const int rg = m0 + wm + mi * 16 + 4 * lg + r;
        const float val = acc[mi][ni][r] + bv;
        if constexpr (MODE == 2) {
          ((float*)out_)[(size_t)rg * 512 + c] = val;
        } else {
          const int bI = rg >> 10, s = rg & 1023, hI = c >> 6, d = c & 63;
          size_t addr;
          if constexpr (MODE == 0)
            // fragment-major qh/kh: [sblk][ks][lg][lr=s&15][j=d&7]
            addr = ((size_t)(bI * 8 + hI) << 16) + (s >> 4) * 1024 + (d >> 5) * 512 +
                   ((d >> 3) & 3) * 128 + (s & 15) * 8 + (d & 7);
          else
            // fragment-major vt: [kt][ni][ks][lg][lr=d&15][j=s&7]
            addr = ((size_t)(bI * 8 + hI) << 16) + (s >> 6) * 4096 + (d >> 4) * 1024 +
                   ((s >> 5) & 1) * 512 + ((s >> 3) & 3) * 128 + (d & 15) * 8 + (s & 7);
          ((unsigned short*)out_)[addr] = f2bf(val);
        }
      }
    }
  }
}

// Fused attention v4: fragment-major Q/K/V (coalesced 1KB frag loads),
// double-buffered bf16 LDS (2 barriers/tile), swapped QK^T, in-place prob
// write-back, direct nontemporal attn stores, XCD-swizzled work assignment.
__global__ __launch_bounds__(512, 4) void attn_fused(
    const unsigned short* __restrict__ qh, const unsigned short* __restrict__ kh,
    const unsigned short* __restrict__ vt, const int* __restrict__ mask,
    float* __restrict__ attn_out, unsigned short* __restrict__ ctx) {
  __shared__ unsigned short sb[2][8][32][72];  // bf16 logits->probs, dbuf

  const int tid = threadIdx.x;
  const int h = tid >> 6, lane = tid & 63;
  const int lr = lane & 15, lg = lane >> 4;

  const int lin = blockIdx.x + 32 * blockIdx.y;
  const int xcd = lin & 7, slot = lin >> 3;
  const int b = xcd + 8 * (slot >> 5);
  const int q0 = (slot & 31) * 32;

  const unsigned short* qb = qh + ((size_t)(b * 8 + h) << 16);
  const unsigned short* kb = kh + ((size_t)(b * 8 + h) << 16);
  const unsigned short* vb = vt + ((size_t)(b * 8 + h) << 16);
  const int* mrow = mask + b * 1024;

  // Q fragments: coalesced (addr = blockbase + lane*8)
  short8 qf[2][2];
#pragma unroll
  for (int qi = 0; qi < 2; ++qi)
#pragma unroll
    for (int ks = 0; ks < 2; ++ks)
      qf[qi][ks] = *(const short8*)(qb + ((q0 >> 4) + qi) * 1024 + ks * 512 + lane * 8);

  const int sq = tid >> 4, sk4 = tid & 15;

  f32x4 apv[2][4] = {};

  for (int kt = 0; kt < 16; ++kt) {
    const int k0 = kt * 64;
    unsigned short(*sc)[32][72] = sb[kt & 1];

    // ---- swapped QK^T; K fragments coalesced
    short8 kf[4][2];
#pragma unroll
    for (int ki = 0; ki < 4; ++ki)
#pragma unroll
      for (int ks = 0; ks < 2; ++ks)
        kf[ki][ks] = *(const short8*)(kb + ((k0 >> 4) + ki) * 1024 + ks * 512 + lane * 8);
    f32x4 aqk[4][2] = {};
#pragma unroll
    for (int ks = 0; ks < 2; ++ks)
#pragma unroll
      for (int ki = 0; ki < 4; ++ki)
#pragma unroll
        for (int qi = 0; qi < 2; ++qi)
          aqk[ki][qi] = MFMA16(kf[ki][ks], qf[qi][ks], aqk[ki][qi]);

    // ---- logit stores (bf16) into sb[kt&1]; WAR on this buffer was cleared
    //      by the barriers of tile kt-1 (PV of kt-2 drained at B1(kt-1)).
#pragma unroll
    for (int ki = 0; ki < 4; ++ki) {
      int4_t mq = *(const int4_t*)(mrow + k0 + ki * 16 + 4 * lg);
      f32x4 mv;
#pragma unroll
      for (int r = 0; r < 4; ++r) mv[r] = -1e9f * (float)mq[r];
#pragma unroll
      for (int qi = 0; qi < 2; ++qi) {
        ushort4_t pk;
#pragma unroll
        for (int r = 0; r < 4; ++r) pk[r] = f2bf(aqk[ki][qi][r] * 0.125f + mv[r]);
        *(ushort4_t*)&sc[h][qi * 16 + lr][ki * 16 + 4 * lg] = pk;
      }
    }
    __syncthreads();  // B1: logits visible to softmax threads

    // ---- softmax over 8 heads; thread owns (sq, 4 k); in-place write-back
    f32x4 e[8];
#pragma unroll
    for (int hh = 0; hh < 8; ++hh) {
      ushort4_t raw = *(const ushort4_t*)&sc[hh][sq][4 * sk4];
#pragma unroll
      for (int r = 0; r < 4; ++r) e[hh][r] = bf2f(raw[r]);
    }
    f32x4 mx = e[0];
#pragma unroll
    for (int hh = 1; hh < 8; ++hh)
#pragma unroll
      for (int r = 0; r < 4; ++r) mx[r] = fmaxf(mx[r], e[hh][r]);
    f32x4 s = {0.f, 0.f, 0.f, 0.f};
#pragma unroll
    for (int hh = 0; hh < 8; ++hh) {
#pragma unroll
      for (int r = 0; r < 4; ++r) e[hh][r] = __expf(e[hh][r] - mx[r]);
      s += e[hh];
    }
    f32x4 inv;
#pragma unroll
    for (int r = 0; r < 4; ++r) inv[r] = __builtin_amdgcn_rcpf(s[r]);

    float* abase = attn_out + (((size_t)(b * 8) * 1024 + q0 + sq) * 1024) + k0 + 4 * sk4;
#pragma unroll
    for (int hh = 0; hh < 8; ++hh) {
      f32x4 p = e[hh] * inv;
      __builtin_nontemporal_store(p, (f32x4*)(abase + ((size_t)hh << 20)));
      ushort4_t pk;
#pragma unroll
      for (int r = 0; r < 4; ++r) pk[r] = f2bf(p[r]);
      *(ushort4_t*)&sc[hh][sq][4 * sk4] = pk;  // same-thread in-place rewrite
    }
    __syncthreads();  // B2: probs visible to PV

    // ---- PV: A = probs (LDS), B = V fragments (coalesced global)
    short8 pf[2][2];
#pragma unroll
    for (int mi = 0; mi < 2; ++mi)
#pragma unroll
      for (int ks = 0; ks < 2; ++ks)
        pf[mi][ks] = *(const short8*)&sc[h][mi * 16 + lr][ks * 32 + 8 * lg];
    short8 vf[4][2];
#pragma unroll
    for (int ni = 0; ni < 4; ++ni)
#pragma unroll
      for (int ks = 0; ks < 2; ++ks)
        vf[ni][ks] = *(const short8*)(vb + kt * 4096 + ni * 1024 + ks * 512 + lane * 8);
#pragma unroll
    for (int ks = 0; ks < 2; ++ks)
#pragma unroll
      for (int mi = 0; mi < 2; ++mi)
#pragma unroll
        for (int ni = 0; ni < 4; ++ni)
          apv[mi][ni] = MFMA16(pf[mi][ks], vf[ni][ks], apv[mi][ni]);
  }

  // ---- write merged ctx [B,S,512] bf16
#pragma unroll
  for (int mi = 0; mi < 2; ++mi)
#pragma unroll
    for (int ni = 0; ni < 4; ++ni)
#pragma unroll
      for (int r = 0; r < 4; ++r) {
        const int row = q0 + mi * 16 + 4 * lg + r;
        const int col = h * 64 + ni * 16 + lr;
        ctx[((size_t)b * 1024 + row) * 512 + col] = f2bf(apv[mi][ni][r]);
      }
}

extern "C" void kernel_launch(void* const* d_in, const int* in_sizes, int n_in,
                              void* d_out, int out_size, void* d_ws, size_t ws_size,
                              hipStream_t stream) {
  const float* q = (const float*)d_in[0];
  const float* k = (const float*)d_in[1];
  const float* v = (const float*)d_in[2];
  const int* mask = (const int*)d_in[3];
  const float* wq_w = (const float*)d_in[4];
  const float* wq_b = (const float*)d_in[5];
  const float* wk_w = (const float*)d_in[6];
  const float* wk_b = (const float*)d_in[7];
  const float* wv_w = (const float*)d_in[8];
  const float* wv_b = (const float*)d_in[9];
  const float* wo_w = (const float*)d_in[10];
  const float* wo_b = (const float*)d_in[11];

  float* out = (float*)d_out;                   // [16,1024,512]
  float* attn = out + (size_t)16 * 1024 * 512;  // [16,8,1024,1024] fp32

  // bf16 staging for buffers consumed BEFORE attn_fused, in the attn tail
  // (attn_fused overwrites the whole region afterwards):
  unsigned short* qb16 = (unsigned short*)(attn + (134217728 - 12976128));
  unsigned short* kb16 = qb16 + (size_t)16 * 1024 * 512;
  unsigned short* vb16 = kb16 + (size_t)16 * 1024 * 512;
  unsigned short* wq16 = vb16 + (size_t)16 * 1024 * 512;
  unsigned short* wk16 = wq16 + 262144;
  unsigned short* wv16 = wk16 + 262144;

  unsigned short* qh = (unsigned short*)d_ws;              // frag-major [B,H][...]
  unsigned short* kh = qh + (size_t)16 * 8 * 1024 * 64;
  unsigned short* vt = kh + (size_t)16 * 8 * 1024 * 64;
  unsigned short* ctx = vt + (size_t)16 * 8 * 1024 * 64;   // [16,1024,512]
  unsigned short* wo16 = ctx + (size_t)16 * 1024 * 512;    // survives attn_fused

  cvt7<<<dim3(12800), dim3(256), 0, stream>>>(q, k, v, wq_w, wk_w, wv_w, wo_w,
                                              qb16, kb16, vb16, wq16, wk16, wv16, wo16);

  dim3 gp(128, 4), bp(256);
  gemm_bt<0><<<gp, bp, 0, stream>>>(qb16, wq16, wq_b, qh);
  gemm_bt<0><<<gp, bp, 0, stream>>>(kb16, wk16, wk_b, kh);
  gemm_bt<1><<<gp, bp, 0, stream>>>(vb16, wv16, wv_b, vt);
  attn_fused<<<dim3(32, 16), dim3(512), 0, stream>>>(qh, kh, vt, mask, attn, ctx);
  gemm_bt<2><<<gp, bp, 0, stream>>>(ctx, wo16, wo_b, out);
}

// Round 7
// 246.242 us; speedup vs baseline: 2.0518x; 1.1023x over previous
//
#include <hip/hip_runtime.h>
#include <math.h>

typedef __attribute__((ext_vector_type(8))) short short8;
typedef __attribute__((ext_vector_type(4))) float f32x4;
typedef __attribute__((ext_vector_type(4))) int int4_t;
typedef __attribute__((ext_vector_type(4))) unsigned short ushort4_t;

#define MFMA16(a, b, c) __builtin_amdgcn_mfma_f32_16x16x32_bf16((a), (b), (c), 0, 0, 0)

// coalesced global->LDS DMA, 16B per lane; LDS dest is wave-uniform base + lane*16
#define GLOAD_LDS16(src, ldsbase)                                                     \
  __builtin_amdgcn_global_load_lds(                                                   \
      (const __attribute__((address_space(1))) void*)(src),                           \
      (__attribute__((address_space(3))) void*)(ldsbase), 16, 0, 0)

static __device__ __forceinline__ unsigned short f2bf(float f) {
  union { float f; unsigned u; } v; v.f = f;
  unsigned r = v.u + 0x7FFFu + ((v.u >> 16) & 1u);
  return (unsigned short)(r >> 16);
}

static __device__ __forceinline__ float bf2f(unsigned short b) {
  union { unsigned u; float f; } v; v.u = ((unsigned)b) << 16;
  return v.f;
}

static __device__ __forceinline__ short8 cvt2v(f32x4 a, f32x4 b) {
  short8 t;
#pragma unroll
  for (int j = 0; j < 4; ++j) t[j] = (short)f2bf(a[j]);
#pragma unroll
  for (int j = 0; j < 4; ++j) t[4 + j] = (short)f2bf(b[j]);
  return t;
}

// Barrier that waits only LDS (lgkmcnt), NOT vmcnt: lets nontemporal global
// stores stay in flight across tiles. Only legal when no barrier-carried
// dependency goes through global memory and no global_load_lds is pending.
static __device__ __forceinline__ void lds_barrier() {
  __builtin_amdgcn_sched_barrier(0);
  asm volatile("s_waitcnt lgkmcnt(0)" ::: "memory");
  __builtin_amdgcn_s_barrier();
  __builtin_amdgcn_sched_barrier(0);
}

// fp32->bf16 conversion of the four weight matrices only (512 blocks).
__global__ __launch_bounds__(256) void cvt_w(
    const float* __restrict__ wq, const float* __restrict__ wk,
    const float* __restrict__ wv, const float* __restrict__ wo,
    unsigned short* __restrict__ wq16, unsigned short* __restrict__ wk16,
    unsigned short* __restrict__ wv16, unsigned short* __restrict__ wo16) {
  const int blk = blockIdx.x;
  const float* src;
  unsigned short* dst;
  size_t base;
  if (blk < 128)      { src = wq; dst = wq16; base = (size_t)blk * 2048; }
  else if (blk < 256) { src = wk; dst = wk16; base = (size_t)(blk - 128) * 2048; }
  else if (blk < 384) { src = wv; dst = wv16; base = (size_t)(blk - 256) * 2048; }
  else                { src = wo; dst = wo16; base = (size_t)(blk - 384) * 2048; }
  const size_t i = base + (size_t)threadIdx.x * 8;
  f32x4 a = *(const f32x4*)(src + i);
  f32x4 b = *(const f32x4*)(src + i + 4);
  *(short8*)(dst + i) = cvt2v(a, b);
}

// LDS-staged bf16 GEMM: C[M,N] = A[M,512] @ W[N,512]^T + bias, fp32 acc.
// AFP32: A is fp32, reg-staged with in-flight bf16 convert; else bf16 gload_lds.
// MODE 0: store bf16 fragment-major qh/kh layout; MODE 1: frag-major vt;
// MODE 2: store fp32 flat [M,512].
template <int MODE, bool AFP32>
__global__ __launch_bounds__(256) void gemm_bt(const void* __restrict__ A_,
                                               const unsigned short* __restrict__ W,
                                               const float* __restrict__ bias,
                                               void* __restrict__ out_) {
  __shared__ unsigned short As[128 * 64], Ws[128 * 64];
  const int tid = threadIdx.x;
  const int wv = tid >> 6, lane = tid & 63;
  const int lr = lane & 15, lg = lane >> 4;
  const int m0 = blockIdx.x * 128, n0 = blockIdx.y * 128;
  const int wm = (wv >> 1) * 64, wn = (wv & 1) * 64;

  f32x4 acc[4][4] = {};

  for (int k0 = 0; k0 < 512; k0 += 64) {
    if constexpr (AFP32) {
      const float* Af = (const float*)A_;
#pragma unroll
      for (int p = 0; p < 4; ++p) {
        const int row = p * 32 + (tid >> 3);
        const int col = (tid & 7) * 8;
        const float* src = Af + (size_t)(m0 + row) * 512 + k0 + col;
        f32x4 a0 = *(const f32x4*)src;
        f32x4 a1 = *(const f32x4*)(src + 4);
        *(short8*)&As[row * 64 + col] = cvt2v(a0, a1);
      }
#pragma unroll
      for (int p = 0; p < 4; ++p) {
        const int row = (p * 4 + wv) * 8 + (lane >> 3);
        const int col = (lane & 7) * 8;
        GLOAD_LDS16(W + (size_t)(n0 + row) * 512 + k0 + col, &Ws[(p * 4 + wv) * 512]);
      }
    } else {
      const unsigned short* Ab = (const unsigned short*)A_;
#pragma unroll
      for (int p = 0; p < 4; ++p) {
        const int row = (p * 4 + wv) * 8 + (lane >> 3);
        const int col = (lane & 7) * 8;
        GLOAD_LDS16(Ab + (size_t)(m0 + row) * 512 + k0 + col, &As[(p * 4 + wv) * 512]);
        GLOAD_LDS16(W + (size_t)(n0 + row) * 512 + k0 + col, &Ws[(p * 4 + wv) * 512]);
      }
    }
    __syncthreads();  // must drain vmcnt (gload_lds) + lgkmcnt (ds_write)

#pragma unroll
    for (int ks = 0; ks < 2; ++ks) {
      short8 af[4], bw[4];
#pragma unroll
      for (int mi = 0; mi < 4; ++mi)
        af[mi] = *(const short8*)&As[(wm + mi * 16 + lr) * 64 + ks * 32 + lg * 8];
#pragma unroll
      for (int ni = 0; ni < 4; ++ni)
        bw[ni] = *(const short8*)&Ws[(wn + ni * 16 + lr) * 64 + ks * 32 + lg * 8];
#pragma unroll
      for (int mi = 0; mi < 4; ++mi)
#pragma unroll
        for (int ni = 0; ni < 4; ++ni)
          acc[mi][ni] = MFMA16(af[mi], bw[ni], acc[mi][ni]);
    }
    __syncthreads();
  }

#pragma unroll
  for (int ni = 0; ni < 4; ++ni) {
    const int c = n0 + wn + ni * 16 + lr;
    const float bv = bias[c];
#pragma unroll
    for (int mi = 0; mi < 4; ++mi) {
#pragma unroll
      for (int r = 0; r < 4; ++r) {
        const int rg = m0 + wm + mi * 16 + 4 * lg + r;
        const float val = acc[mi][ni][r] + bv;
        if constexpr (MODE == 2) {
          ((float*)out_)[(size_t)rg * 512 + c] = val;
        } else {
          const int bI = rg >> 10, s = rg & 1023, hI = c >> 6, d = c & 63;
          size_t addr;
          if constexpr (MODE == 0)
            // fragment-major qh/kh: [sblk][ks][lg][lr=s&15][j=d&7]
            addr = ((size_t)(bI * 8 + hI) << 16) + (s >> 4) * 1024 + (d >> 5) * 512 +
                   ((d >> 3) & 3) * 128 + (s & 15) * 8 + (d & 7);
          else
            // fragment-major vt: [kt][ni][ks][lg][lr=d&15][j=s&7]
            addr = ((size_t)(bI * 8 + hI) << 16) + (s >> 6) * 4096 + (d >> 4) * 1024 +
                   ((s >> 5) & 1) * 512 + ((s >> 3) & 3) * 128 + (d & 15) * 8 + (s & 7);
          ((unsigned short*)out_)[addr] = f2bf(val);
        }
      }
    }
  }
}

// Fused attention v5: fragment-major Q/K/V (coalesced 1KB frag loads),
// double-buffered bf16 LDS, lgkm-only barriers (nt attn stores stream
// across tiles), swapped QK^T, in-place prob write-back, XCD swizzle.
__global__ __launch_bounds__(512, 4) void attn_fused(
    const unsigned short* __restrict__ qh, const unsigned short* __restrict__ kh,
    const unsigned short* __restrict__ vt, const int* __restrict__ mask,
    float* __restrict__ attn_out, unsigned short* __restrict__ ctx) {
  __shared__ unsigned short sb[2][8][32][72];  // bf16 logits->probs, dbuf

  const int tid = threadIdx.x;
  const int h = tid >> 6, lane = tid & 63;
  const int lr = lane & 15, lg = lane >> 4;

  const int lin = blockIdx.x + 32 * blockIdx.y;
  const int xcd = lin & 7, slot = lin >> 3;
  const int b = xcd + 8 * (slot >> 5);
  const int q0 = (slot & 31) * 32;

  const unsigned short* qb = qh + ((size_t)(b * 8 + h) << 16);
  const unsigned short* kb = kh + ((size_t)(b * 8 + h) << 16);
  const unsigned short* vb = vt + ((size_t)(b * 8 + h) << 16);
  const int* mrow = mask + b * 1024;

  short8 qf[2][2];
#pragma unroll
  for (int qi = 0; qi < 2; ++qi)
#pragma unroll
    for (int ks = 0; ks < 2; ++ks)
      qf[qi][ks] = *(const short8*)(qb + ((q0 >> 4) + qi) * 1024 + ks * 512 + lane * 8);

  const int sq = tid >> 4, sk4 = tid & 15;

  f32x4 apv[2][4] = {};

  for (int kt = 0; kt < 16; ++kt) {
    const int k0 = kt * 64;
    unsigned short(*sc)[32][72] = sb[kt & 1];

    // ---- swapped QK^T; K fragments coalesced
    short8 kf[4][2];
#pragma unroll
    for (int ki = 0; ki < 4; ++ki)
#pragma unroll
      for (int ks = 0; ks < 2; ++ks)
        kf[ki][ks] = *(const short8*)(kb + ((k0 >> 4) + ki) * 1024 + ks * 512 + lane * 8);
    f32x4 aqk[4][2] = {};
#pragma unroll
    for (int ks = 0; ks < 2; ++ks)
#pragma unroll
      for (int ki = 0; ki < 4; ++ki)
#pragma unroll
        for (int qi = 0; qi < 2; ++qi)
          aqk[ki][qi] = MFMA16(kf[ki][ks], qf[qi][ks], aqk[ki][qi]);

    // ---- logit stores (bf16) into sb[kt&1]; WAR cleared by tile kt-1 barriers
#pragma unroll
    for (int ki = 0; ki < 4; ++ki) {
      int4_t mq = *(const int4_t*)(mrow + k0 + ki * 16 + 4 * lg);
      f32x4 mv;
#pragma unroll
      for (int r = 0; r < 4; ++r) mv[r] = -1e9f * (float)mq[r];
#pragma unroll
      for (int qi = 0; qi < 2; ++qi) {
        ushort4_t pk;
#pragma unroll
        for (int r = 0; r < 4; ++r) pk[r] = f2bf(aqk[ki][qi][r] * 0.125f + mv[r]);
        *(ushort4_t*)&sc[h][qi * 16 + lr][ki * 16 + 4 * lg] = pk;
      }
    }
    lds_barrier();  // B1: logits visible; nt stores keep streaming

    // ---- softmax over 8 heads; thread owns (sq, 4 k); in-place write-back
    f32x4 e[8];
#pragma unroll
    for (int hh = 0; hh < 8; ++hh) {
      ushort4_t raw = *(const ushort4_t*)&sc[hh][sq][4 * sk4];
#pragma unroll
      for (int r = 0; r < 4; ++r) e[hh][r] = bf2f(raw[r]);
    }
    f32x4 mx = e[0];
#pragma unroll
    for (int hh = 1; hh < 8; ++hh)
#pragma unroll
      for (int r = 0; r < 4; ++r) mx[r] = fmaxf(mx[r], e[hh][r]);
    f32x4 s = {0.f, 0.f, 0.f, 0.f};
#pragma unroll
    for (int hh = 0; hh < 8; ++hh) {
#pragma unroll
      for (int r = 0; r < 4; ++r) e[hh][r] = __expf(e[hh][r] - mx[r]);
      s += e[hh];
    }
    f32x4 inv;
#pragma unroll
    for (int r = 0; r < 4; ++r) inv[r] = __builtin_amdgcn_rcpf(s[r]);

    float* abase = attn_out + (((size_t)(b * 8) * 1024 + q0 + sq) * 1024) + k0 + 4 * sk4;
#pragma unroll
    for (int hh = 0; hh < 8; ++hh) {
      f32x4 p = e[hh] * inv;
      __builtin_nontemporal_store(p, (f32x4*)(abase + ((size_t)hh << 20)));
      ushort4_t pk;
#pragma unroll
      for (int r = 0; r < 4; ++r) pk[r] = f2bf(p[r]);
      *(ushort4_t*)&sc[hh][sq][4 * sk4] = pk;  // same-thread in-place rewrite
    }
    lds_barrier();  // B2: probs visible to PV

    // ---- PV: A = probs (LDS), B = V fragments (coalesced global)
    short8 pf[2][2];
#pragma unroll
    for (int mi = 0; mi < 2; ++mi)
#pragma unroll
      for (int ks = 0; ks < 2; ++ks)
        pf[mi][ks] = *(const short8*)&sc[h][mi * 16 + lr][ks * 32 + 8 * lg];
    short8 vf[4][2];
#pragma unroll
    for (int ni = 0; ni < 4; ++ni)
#pragma unroll
      for (int ks = 0; ks < 2; ++ks)
        vf[ni][ks] = *(const short8*)(vb + kt * 4096 + ni * 1024 + ks * 512 + lane * 8);
#pragma unroll
    for (int ks = 0; ks < 2; ++ks)
#pragma unroll
      for (int mi = 0; mi < 2; ++mi)
#pragma unroll
        for (int ni = 0; ni < 4; ++ni)
          apv[mi][ni] = MFMA16(pf[mi][ks], vf[ni][ks], apv[mi][ni]);
  }

  // ---- write merged ctx [B,S,512] bf16
#pragma unroll
  for (int mi = 0; mi < 2; ++mi)
#pragma unroll
    for (int ni = 0; ni < 4; ++ni)
#pragma unroll
      for (int r = 0; r < 4; ++r) {
        const int row = q0 + mi * 16 + 4 * lg + r;
        const int col = h * 64 + ni * 16 + lr;
        ctx[((size_t)b * 1024 + row) * 512 + col] = f2bf(apv[mi][ni][r]);
      }
}

extern "C" void kernel_launch(void* const* d_in, const int* in_sizes, int n_in,
                              void* d_out, int out_size, void* d_ws, size_t ws_size,
                              hipStream_t stream) {
  const float* q = (const float*)d_in[0];
  const float* k = (const float*)d_in[1];
  const float* v = (const float*)d_in[2];
  const int* mask = (const int*)d_in[3];
  const float* wq_w = (const float*)d_in[4];
  const float* wq_b = (const float*)d_in[5];
  const float* wk_w = (const float*)d_in[6];
  const float* wk_b = (const float*)d_in[7];
  const float* wv_w = (const float*)d_in[8];
  const float* wv_b = (const float*)d_in[9];
  const float* wo_w = (const float*)d_in[10];
  const float* wo_b = (const float*)d_in[11];

  float* out = (float*)d_out;                   // [16,1024,512]
  float* attn = out + (size_t)16 * 1024 * 512;  // [16,8,1024,1024] fp32

  // bf16 weights consumed BEFORE attn_fused -> attn-tail scratch
  // (3 x 262144 ushorts = 393216 floats)
  unsigned short* wq16 = (unsigned short*)(attn + (134217728 - 393216));
  unsigned short* wk16 = wq16 + 262144;
  unsigned short* wv16 = wk16 + 262144;

  unsigned short* qh = (unsigned short*)d_ws;              // frag-major [B,H][...]
  unsigned short* kh = qh + (size_t)16 * 8 * 1024 * 64;
  unsigned short* vt = kh + (size_t)16 * 8 * 1024 * 64;
  unsigned short* ctx = vt + (size_t)16 * 8 * 1024 * 64;   // [16,1024,512]
  unsigned short* wo16 = ctx + (size_t)16 * 1024 * 512;    // survives attn_fused

  cvt_w<<<dim3(512), dim3(256), 0, stream>>>(wq_w, wk_w, wv_w, wo_w,
                                             wq16, wk16, wv16, wo16);

  dim3 gp(128, 4), bp(256);
  gemm_bt<0, true><<<gp, bp, 0, stream>>>(q, wq16, wq_b, qh);
  gemm_bt<0, true><<<gp, bp, 0, stream>>>(k, wk16, wk_b, kh);
  gemm_bt<1, true><<<gp, bp, 0, stream>>>(v, wv16, wv_b, vt);
  attn_fused<<<dim3(32, 16), dim3(512), 0, stream>>>(qh, kh, vt, mask, attn, ctx);
  gemm_bt<2, false><<<gp, bp, 0, stream>>>(ctx, wo16, wo_b, out);
}